// Round 5
// baseline (546.468 us; speedup 1.0000x reference)
//
#include <hip/hip_runtime.h>
#include <hip/hip_bf16.h>

// DeepseekV3 MoE calibrate: T=1024, H=1024, I=512, E=32, top-8, group-4/top-2.
// Round 5: top-k compaction (skip the 75% of expert work with exactly-zero routing
// weight) + fused g/u GEMM with silu-act epilogue. Baseline (dense, round 4): 519us.

typedef __attribute__((ext_vector_type(8))) short short8v;
typedef __attribute__((ext_vector_type(4))) float f32x4;

#define GLOAD_LDS(gp, lp)                                                      \
  __builtin_amdgcn_global_load_lds(                                            \
      (const __attribute__((address_space(1))) void*)(gp),                     \
      (__attribute__((address_space(3))) void*)(lp), 16, 0, 0)

__device__ __forceinline__ unsigned short f2bf(float f) {
  unsigned int u = __float_as_uint(f);
  u = (u + 0x7fffu + ((u >> 16) & 1u)) >> 16;
  return (unsigned short)u;
}
__device__ __forceinline__ float bf2f(unsigned short b) {
  return __uint_as_float(((unsigned int)b) << 16);
}

// ---------------- fp32 -> bf16 conversion ----------------
__global__ void convert_kernel(const float* __restrict__ src,
                               unsigned short* __restrict__ dst, long n) {
  long i = ((long)blockIdx.x * blockDim.x + threadIdx.x) * 4;
  long stride = (long)gridDim.x * blockDim.x * 4;
  for (; i < n; i += stride) {
    float4 v = *(const float4*)(src + i);
    ushort4 o;
    o.x = f2bf(v.x); o.y = f2bf(v.y); o.z = f2bf(v.z); o.w = f2bf(v.w);
    *(ushort4*)(dst + i) = o;
  }
}

// ---------------- routing (DeepseekV3TopkRouter) ----------------
// One block per token. Produces dense W[t][32]: topk_w * 2.5 at selected, else 0.
__global__ void gate_kernel(const float* __restrict__ x, const float* __restrict__ gw,
                            const float* __restrict__ gb, float* __restrict__ W) {
  int t = blockIdx.x;
  int tid = threadIdx.x;
  __shared__ float partial[256];
  __shared__ float logits[32];
  const float* xr = x + (long)t * 1024;
  int e = tid & 31, c = tid >> 5;
  const float* wr = gw + (long)e * 1024 + c * 128;
  const float* xc = xr + c * 128;
  float s = 0.f;
  for (int h = 0; h < 128; h += 4) {
    float4 xv = *(const float4*)(xc + h);
    float4 wv = *(const float4*)(wr + h);
    s += xv.x * wv.x + xv.y * wv.y + xv.z * wv.z + xv.w * wv.w;
  }
  partial[tid] = s;
  __syncthreads();
  if (tid < 32) {
    float l = 0.f;
    for (int cc = 0; cc < 8; cc++) l += partial[tid + 32 * cc];
    logits[tid] = l;
  }
  __syncthreads();
  if (tid == 0) {
    float scores[32], sc[32];
    for (int i = 0; i < 32; i++) {
      float s1 = 1.f / (1.f + expf(-logits[i]));
      scores[i] = s1;
      sc[i] = s1 + gb[i];
    }
    float gsc[4];
    for (int g = 0; g < 4; g++) {
      float m1 = -1e30f, m2 = -1e30f;
      for (int j = 0; j < 8; j++) {
        float v = sc[g * 8 + j];
        if (v > m1) { m2 = m1; m1 = v; }
        else if (v > m2) m2 = v;
      }
      gsc[g] = m1 + m2;
    }
    int g1 = 0;
    for (int g = 1; g < 4; g++) if (gsc[g] > gsc[g1]) g1 = g;
    int g2 = -1;
    for (int g = 0; g < 4; g++) {
      if (g == g1) continue;
      if (g2 < 0 || gsc[g] > gsc[g2]) g2 = g;
    }
    float masked[32];
    for (int i = 0; i < 32; i++) {
      int g = i >> 3;
      masked[i] = (g == g1 || g == g2) ? sc[i] : 0.0f;
    }
    int idx[8]; float tw[8]; float wsum = 0.f;
    for (int k = 0; k < 8; k++) {
      int best = 0; float bv = -1e30f;
      for (int i = 0; i < 32; i++) if (masked[i] > bv) { bv = masked[i]; best = i; }
      idx[k] = best;
      masked[best] = -2e30f;
      tw[k] = scores[best];
      wsum += tw[k];
    }
    float inv = 2.5f / (wsum + 1e-20f);
    float wout[32];
    for (int i = 0; i < 32; i++) wout[i] = 0.f;
    for (int k = 0; k < 8; k++) wout[idx[k]] = tw[k] * inv;
    for (int i = 0; i < 32; i++) W[t * 32 + i] = wout[i];
  }
}

// ---------------- per-expert token lists ----------------
__global__ void build_lists_kernel(const float* __restrict__ W, int* __restrict__ counts,
                                   int* __restrict__ tok) {
  int i = blockIdx.x * blockDim.x + threadIdx.x;  // i = t*32 + e
  if (i < 32768) {
    if (W[i] != 0.f) {
      int t = i >> 5, e = i & 31;
      int p = atomicAdd(&counts[e], 1);
      tok[e * 1024 + p] = t;
    }
  }
}

// ---------------- fused g/u GEMM + silu-act epilogue ----------------
// A = xb [1024,1024] (rows gathered via tok when non-null). Bg/Bu [N,1024] per expert.
// Writes Act[e][row][col] = silu(g)*u*W bf16 for row < count. K=1024 fixed.
// LDS XOR-swizzle (chunk ^= row&7) via pre-swizzled global source; linear LDS dest.
__global__ __launch_bounds__(256) void gemm_gu_act_kernel(
    const unsigned short* __restrict__ A, const unsigned short* __restrict__ BgAll,
    const unsigned short* __restrict__ BuAll, unsigned short* __restrict__ ActAll,
    const int* __restrict__ tok, const int* __restrict__ counts,
    const float* __restrict__ W, int ldO, long strideB, long strideO) {
  __shared__ unsigned short As[128 * 64];
  __shared__ unsigned short Bgs[128 * 64];
  __shared__ unsigned short Bus[128 * 64];
  int n0 = blockIdx.x * 128, m0 = blockIdx.y * 128;
  int e = blockIdx.z;
  int count = counts ? counts[e] : 1024;
  if (m0 >= count) return;
  const unsigned short* Bg = BgAll + (long)e * strideB;
  const unsigned short* Bu = BuAll + (long)e * strideB;

  int tid = threadIdx.x;
  int lane = tid & 63;
  int w = tid >> 6;
  int lrow = lane >> 3;
  int lslot = lane & 7;
  int csrc = lslot ^ lrow;
  int wr = w >> 1, wc = w & 1;
  int lm = lane & 15, lk = lane >> 4;

  // gathered A-row per staging stripe (constant across K-steps)
  int rowA[4];
#pragma unroll
  for (int r = 0; r < 4; r++) {
    int mrow = m0 + r * 32 + w * 8 + lrow;
    int cl = mrow < count ? mrow : count - 1;
    rowA[r] = tok ? tok[e * 1024 + cl] : mrow;
  }

  f32x4 zero = {0.f, 0.f, 0.f, 0.f};
  f32x4 accg[4][4], accu[4][4];
#pragma unroll
  for (int mi = 0; mi < 4; mi++)
#pragma unroll
    for (int ni = 0; ni < 4; ni++) { accg[mi][ni] = zero; accu[mi][ni] = zero; }

  for (int k0 = 0; k0 < 1024; k0 += 64) {
    __syncthreads();
#pragma unroll
    for (int r = 0; r < 4; r++) {
      int stripe = r * 32 + w * 8;
      GLOAD_LDS(A + (long)rowA[r] * 1024 + k0 + csrc * 8, As + stripe * 64);
    }
#pragma unroll
    for (int r = 0; r < 4; r++) {
      int stripe = r * 32 + w * 8;
      const unsigned short* gp = Bg + (long)(n0 + stripe + lrow) * 1024 + k0 + csrc * 8;
      GLOAD_LDS(gp, Bgs + stripe * 64);
    }
#pragma unroll
    for (int r = 0; r < 4; r++) {
      int stripe = r * 32 + w * 8;
      const unsigned short* gp = Bu + (long)(n0 + stripe + lrow) * 1024 + k0 + csrc * 8;
      GLOAD_LDS(gp, Bus + stripe * 64);
    }
    __syncthreads();
#pragma unroll
    for (int ks = 0; ks < 2; ks++) {
      short8v af[4], bg[4], bu[4];
#pragma unroll
      for (int mi = 0; mi < 4; mi++) {
        int rA = wr * 64 + mi * 16 + lm;
        int cA = ks * 4 + lk;
        af[mi] = *(const short8v*)(As + rA * 64 + ((cA ^ (rA & 7)) * 8));
      }
#pragma unroll
      for (int ni = 0; ni < 4; ni++) {
        int rB = wc * 64 + ni * 16 + lm;
        int cB = ks * 4 + lk;
        bg[ni] = *(const short8v*)(Bgs + rB * 64 + ((cB ^ (rB & 7)) * 8));
        bu[ni] = *(const short8v*)(Bus + rB * 64 + ((cB ^ (rB & 7)) * 8));
      }
#pragma unroll
      for (int mi = 0; mi < 4; mi++)
#pragma unroll
        for (int ni = 0; ni < 4; ni++) {
          accg[mi][ni] = __builtin_amdgcn_mfma_f32_16x16x32_bf16(af[mi], bg[ni],
                                                                 accg[mi][ni], 0, 0, 0);
          accu[mi][ni] = __builtin_amdgcn_mfma_f32_16x16x32_bf16(af[mi], bu[ni],
                                                                 accu[mi][ni], 0, 0, 0);
        }
    }
  }
  unsigned short* Act = ActAll + (long)e * strideO;
#pragma unroll
  for (int mi = 0; mi < 4; mi++) {
#pragma unroll
    for (int j = 0; j < 4; j++) {
      int row = m0 + wr * 64 + mi * 16 + lk * 4 + j;
      if (row >= count) continue;
      float wv = 1.f;
      if (W) { int tk = tok[e * 1024 + row]; wv = W[tk * 32 + e]; }
#pragma unroll
      for (int ni = 0; ni < 4; ni++) {
        int col = n0 + wc * 64 + ni * 16 + lm;
        float gf = accg[mi][ni][j], uf = accu[mi][ni][j];
        float a = gf / (1.f + expf(-gf)) * uf * wv;
        Act[(long)row * ldO + col] = f2bf(a);
      }
    }
  }
}

// ---------------- down projection, compacted rows, scatter-add ----------------
// A = Act[e] (compacted rows), B = down[e] [1024,512], out[tok[row]][col] += v.
__global__ __launch_bounds__(256) void gemm_down_gather_kernel(
    const unsigned short* __restrict__ ActAll, const unsigned short* __restrict__ BdAll,
    float* __restrict__ C, const int* __restrict__ tok, const int* __restrict__ counts) {
  __shared__ unsigned short As[128 * 64];
  __shared__ unsigned short Bs[128 * 64];
  int n0 = blockIdx.x * 128, m0 = blockIdx.y * 128;
  int e = blockIdx.z;
  int count = counts[e];
  if (m0 >= count) return;
  const unsigned short* Ag = ActAll + (long)e * 524288;
  const unsigned short* Bg = BdAll + (long)e * 524288;

  int tid = threadIdx.x;
  int lane = tid & 63;
  int w = tid >> 6;
  int lrow = lane >> 3;
  int lslot = lane & 7;
  int csrc = lslot ^ lrow;
  int wr = w >> 1, wc = w & 1;
  int lm = lane & 15, lk = lane >> 4;

  f32x4 zero = {0.f, 0.f, 0.f, 0.f};
  f32x4 acc[4][4];
#pragma unroll
  for (int mi = 0; mi < 4; mi++)
#pragma unroll
    for (int ni = 0; ni < 4; ni++) acc[mi][ni] = zero;

  for (int k0 = 0; k0 < 512; k0 += 64) {
    __syncthreads();
#pragma unroll
    for (int r = 0; r < 4; r++) {
      int stripe = r * 32 + w * 8;
      GLOAD_LDS(Ag + (long)(m0 + stripe + lrow) * 512 + k0 + csrc * 8, As + stripe * 64);
    }
#pragma unroll
    for (int r = 0; r < 4; r++) {
      int stripe = r * 32 + w * 8;
      GLOAD_LDS(Bg + (long)(n0 + stripe + lrow) * 512 + k0 + csrc * 8, Bs + stripe * 64);
    }
    __syncthreads();
#pragma unroll
    for (int ks = 0; ks < 2; ks++) {
      short8v af[4], bv[4];
#pragma unroll
      for (int mi = 0; mi < 4; mi++) {
        int rA = wr * 64 + mi * 16 + lm;
        int cA = ks * 4 + lk;
        af[mi] = *(const short8v*)(As + rA * 64 + ((cA ^ (rA & 7)) * 8));
      }
#pragma unroll
      for (int ni = 0; ni < 4; ni++) {
        int rB = wc * 64 + ni * 16 + lm;
        int cB = ks * 4 + lk;
        bv[ni] = *(const short8v*)(Bs + rB * 64 + ((cB ^ (rB & 7)) * 8));
      }
#pragma unroll
      for (int mi = 0; mi < 4; mi++)
#pragma unroll
        for (int ni = 0; ni < 4; ni++)
          acc[mi][ni] = __builtin_amdgcn_mfma_f32_16x16x32_bf16(af[mi], bv[ni],
                                                                acc[mi][ni], 0, 0, 0);
    }
  }
#pragma unroll
  for (int mi = 0; mi < 4; mi++) {
#pragma unroll
    for (int j = 0; j < 4; j++) {
      int row = m0 + wr * 64 + mi * 16 + lk * 4 + j;
      if (row >= count) continue;
      int tk = tok[e * 1024 + row];
#pragma unroll
      for (int ni = 0; ni < 4; ni++) {
        int col = n0 + wc * 64 + ni * 16 + lm;
        atomicAdd(&C[(long)tk * 1024 + col], acc[mi][ni][j]);
      }
    }
  }
}

// Dense down (shared path): C[T,1024] fp32 += A @ B^T, atomic accumulate.
__global__ __launch_bounds__(256) void gemm_down_kernel(
    const unsigned short* __restrict__ A, const unsigned short* __restrict__ B,
    float* __restrict__ C, int ldA, int ldB, int K) {
  __shared__ unsigned short As[128 * 64];
  __shared__ unsigned short Bs[128 * 64];
  int n0 = blockIdx.x * 128, m0 = blockIdx.y * 128;
  int tid = threadIdx.x;
  int lane = tid & 63;
  int w = tid >> 6;
  int lrow = lane >> 3;
  int lslot = lane & 7;
  int csrc = lslot ^ lrow;
  int wr = w >> 1, wc = w & 1;
  int lm = lane & 15, lk = lane >> 4;
  f32x4 zero = {0.f, 0.f, 0.f, 0.f};
  f32x4 acc[4][4];
#pragma unroll
  for (int mi = 0; mi < 4; mi++)
#pragma unroll
    for (int ni = 0; ni < 4; ni++) acc[mi][ni] = zero;
  for (int k0 = 0; k0 < K; k0 += 64) {
    __syncthreads();
#pragma unroll
    for (int r = 0; r < 4; r++) {
      int stripe = r * 32 + w * 8;
      GLOAD_LDS(A + (long)(m0 + stripe + lrow) * ldA + k0 + csrc * 8, As + stripe * 64);
    }
#pragma unroll
    for (int r = 0; r < 4; r++) {
      int stripe = r * 32 + w * 8;
      GLOAD_LDS(B + (long)(n0 + stripe + lrow) * ldB + k0 + csrc * 8, Bs + stripe * 64);
    }
    __syncthreads();
#pragma unroll
    for (int ks = 0; ks < 2; ks++) {
      short8v af[4], bv[4];
#pragma unroll
      for (int mi = 0; mi < 4; mi++) {
        int rA = wr * 64 + mi * 16 + lm;
        int cA = ks * 4 + lk;
        af[mi] = *(const short8v*)(As + rA * 64 + ((cA ^ (rA & 7)) * 8));
      }
#pragma unroll
      for (int ni = 0; ni < 4; ni++) {
        int rB = wc * 64 + ni * 16 + lm;
        int cB = ks * 4 + lk;
        bv[ni] = *(const short8v*)(Bs + rB * 64 + ((cB ^ (rB & 7)) * 8));
      }
#pragma unroll
      for (int mi = 0; mi < 4; mi++)
#pragma unroll
        for (int ni = 0; ni < 4; ni++)
          acc[mi][ni] = __builtin_amdgcn_mfma_f32_16x16x32_bf16(af[mi], bv[ni],
                                                                acc[mi][ni], 0, 0, 0);
    }
  }
#pragma unroll
  for (int mi = 0; mi < 4; mi++) {
#pragma unroll
    for (int ni = 0; ni < 4; ni++) {
      f32x4 v = acc[mi][ni];
      int col = n0 + wc * 64 + ni * 16 + lm;
      int rbase = m0 + wr * 64 + mi * 16 + lk * 4;
#pragma unroll
      for (int j = 0; j < 4; j++)
        atomicAdd(&C[(long)(rbase + j) * 1024 + col], v[j]);
    }
  }
}

extern "C" void kernel_launch(void* const* d_in, const int* in_sizes, int n_in,
                              void* d_out, int out_size, void* d_ws, size_t ws_size,
                              hipStream_t stream) {
  const float* x  = (const float*)d_in[0];   // [1024,1024]
  const float* gw = (const float*)d_in[1];   // [32,1024]
  const float* gb = (const float*)d_in[2];   // [32]
  const float* eg = (const float*)d_in[3];   // [32,512,1024]
  const float* eu = (const float*)d_in[4];   // [32,512,1024]
  const float* ed = (const float*)d_in[5];   // [32,1024,512]
  const float* sg = (const float*)d_in[6];   // [1024,1024]
  const float* su = (const float*)d_in[7];   // [1024,1024]
  const float* sd = (const float*)d_in[8];   // [1024,1024]
  float* out = (float*)d_out;

  char* ws = (char*)d_ws;
  size_t off = 0;
  auto alloc = [&](size_t bytes) {
    off = (off + 255) & ~(size_t)255;
    void* p = ws + off;
    off += bytes;
    return p;
  };
  unsigned short* xb    = (unsigned short*)alloc(1048576L * 2);
  unsigned short* egb   = (unsigned short*)alloc(16777216L * 2);
  unsigned short* eub   = (unsigned short*)alloc(16777216L * 2);
  unsigned short* edb   = (unsigned short*)alloc(16777216L * 2);
  unsigned short* sgb   = (unsigned short*)alloc(1048576L * 2);
  unsigned short* sub   = (unsigned short*)alloc(1048576L * 2);
  unsigned short* sdb   = (unsigned short*)alloc(1048576L * 2);
  float*          Wrt   = (float*)alloc(1024L * 32 * 4);
  unsigned short* act_c = (unsigned short*)alloc(16777216L * 2);  // [32][1024][512]
  unsigned short* act_s = (unsigned short*)alloc(1048576L * 2);   // [1024][1024]
  int*            counts = (int*)alloc(32 * 4);
  int*            tok    = (int*)alloc(32L * 1024 * 4);

  hipMemsetAsync(counts, 0, 32 * 4, stream);
  hipMemsetAsync(d_out, 0, (size_t)out_size * 4, stream);

  convert_kernel<<<1024, 256, 0, stream>>>(x, xb, 1048576L);
  convert_kernel<<<4096, 256, 0, stream>>>(eg, egb, 16777216L);
  convert_kernel<<<4096, 256, 0, stream>>>(eu, eub, 16777216L);
  convert_kernel<<<4096, 256, 0, stream>>>(ed, edb, 16777216L);
  convert_kernel<<<1024, 256, 0, stream>>>(sg, sgb, 1048576L);
  convert_kernel<<<1024, 256, 0, stream>>>(su, sub, 1048576L);
  convert_kernel<<<1024, 256, 0, stream>>>(sd, sdb, 1048576L);

  gate_kernel<<<1024, 256, 0, stream>>>(x, gw, gb, Wrt);
  build_lists_kernel<<<128, 256, 0, stream>>>(Wrt, counts, tok);

  dim3 blk(256);
  // expert path: fused g/u GEMM + silu*u*W epilogue on compacted token lists
  gemm_gu_act_kernel<<<dim3(4, 8, 32), blk, 0, stream>>>(
      xb, egb, eub, act_c, tok, counts, Wrt, 512, 524288L, 524288L);
  // shared path: same fused kernel, dense rows, weight 1
  gemm_gu_act_kernel<<<dim3(8, 8, 1), blk, 0, stream>>>(
      xb, sgb, sub, act_s, nullptr, nullptr, nullptr, 1024, 0L, 0L);

  // expert down: compacted rows, scatter-add into out
  gemm_down_gather_kernel<<<dim3(8, 8, 32), blk, 0, stream>>>(act_c, edb, out, tok,
                                                              counts);
  // shared down: dense atomic accumulate
  gemm_down_kernel<<<dim3(8, 8, 1), blk, 0, stream>>>(act_s, sdb, out, 1024, 1024, 1024);
}

// Round 9
// 436.097 us; speedup vs baseline: 1.2531x; 1.2531x over previous
//
#include <hip/hip_runtime.h>
#include <hip/hip_bf16.h>

// DeepseekV3 MoE calibrate: T=1024, H=1024, I=512, E=32, top-8.
// Round 9 = round 6 design, 3rd resubmit (rounds 6-8: 2x GPUAcquisitionTimeout,
// 1x "container failed twice" — all infrastructure, kernel never executed).
// Top-k compaction + fixes for the round-5 latency collapse (3.5% occupancy):
// pre-gathered compacted X rows (contiguous staging), work-list planner (no early-exit
// imbalance), 64x128 tiles (2-4x more blocks, 24-40KB LDS). Round-4 dense: 519us,
// round-5 compacted-but-starved: 546us (gu_act 158us at 1 wave/SIMD).

typedef __attribute__((ext_vector_type(8))) short short8v;
typedef __attribute__((ext_vector_type(4))) float f32x4;

#define GLOAD_LDS(gp, lp)                                                      \
  __builtin_amdgcn_global_load_lds(                                            \
      (const __attribute__((address_space(1))) void*)(gp),                     \
      (__attribute__((address_space(3))) void*)(lp), 16, 0, 0)

__device__ __forceinline__ unsigned short f2bf(float f) {
  unsigned int u = __float_as_uint(f);
  u = (u + 0x7fffu + ((u >> 16) & 1u)) >> 16;
  return (unsigned short)u;
}
__device__ __forceinline__ float bf2f(unsigned short b) {
  return __uint_as_float(((unsigned int)b) << 16);
}

// ---------------- fp32 -> bf16 conversion ----------------
__global__ void convert_kernel(const float* __restrict__ src,
                               unsigned short* __restrict__ dst, long n) {
  long i = ((long)blockIdx.x * blockDim.x + threadIdx.x) * 4;
  long stride = (long)gridDim.x * blockDim.x * 4;
  for (; i < n; i += stride) {
    float4 v = *(const float4*)(src + i);
    ushort4 o;
    o.x = f2bf(v.x); o.y = f2bf(v.y); o.z = f2bf(v.z); o.w = f2bf(v.w);
    *(ushort4*)(dst + i) = o;
  }
}

// ---------------- routing ----------------
__global__ void gate_kernel(const float* __restrict__ x, const float* __restrict__ gw,
                            const float* __restrict__ gb, float* __restrict__ W) {
  int t = blockIdx.x;
  int tid = threadIdx.x;
  __shared__ float partial[256];
  __shared__ float logits[32];
  const float* xr = x + (long)t * 1024;
  int e = tid & 31, c = tid >> 5;
  const float* wr = gw + (long)e * 1024 + c * 128;
  const float* xc = xr + c * 128;
  float s = 0.f;
  for (int h = 0; h < 128; h += 4) {
    float4 xv = *(const float4*)(xc + h);
    float4 wv = *(const float4*)(wr + h);
    s += xv.x * wv.x + xv.y * wv.y + xv.z * wv.z + xv.w * wv.w;
  }
  partial[tid] = s;
  __syncthreads();
  if (tid < 32) {
    float l = 0.f;
    for (int cc = 0; cc < 8; cc++) l += partial[tid + 32 * cc];
    logits[tid] = l;
  }
  __syncthreads();
  if (tid == 0) {
    float scores[32], sc[32];
    for (int i = 0; i < 32; i++) {
      float s1 = 1.f / (1.f + expf(-logits[i]));
      scores[i] = s1;
      sc[i] = s1 + gb[i];
    }
    float gsc[4];
    for (int g = 0; g < 4; g++) {
      float m1 = -1e30f, m2 = -1e30f;
      for (int j = 0; j < 8; j++) {
        float v = sc[g * 8 + j];
        if (v > m1) { m2 = m1; m1 = v; }
        else if (v > m2) m2 = v;
      }
      gsc[g] = m1 + m2;
    }
    int g1 = 0;
    for (int g = 1; g < 4; g++) if (gsc[g] > gsc[g1]) g1 = g;
    int g2 = -1;
    for (int g = 0; g < 4; g++) {
      if (g == g1) continue;
      if (g2 < 0 || gsc[g] > gsc[g2]) g2 = g;
    }
    float masked[32];
    for (int i = 0; i < 32; i++) {
      int g = i >> 3;
      masked[i] = (g == g1 || g == g2) ? sc[i] : 0.0f;
    }
    int idx[8]; float tw[8]; float wsum = 0.f;
    for (int k = 0; k < 8; k++) {
      int best = 0; float bv = -1e30f;
      for (int i = 0; i < 32; i++) if (masked[i] > bv) { bv = masked[i]; best = i; }
      idx[k] = best;
      masked[best] = -2e30f;
      tw[k] = scores[best];
      wsum += tw[k];
    }
    float inv = 2.5f / (wsum + 1e-20f);
    float wout[32];
    for (int i = 0; i < 32; i++) wout[i] = 0.f;
    for (int k = 0; k < 8; k++) wout[idx[k]] = tw[k] * inv;
    for (int i = 0; i < 32; i++) W[t * 32 + i] = wout[i];
  }
}

// ---------------- per-expert token lists ----------------
__global__ void build_lists_kernel(const float* __restrict__ W, int* __restrict__ counts,
                                   int* __restrict__ tok) {
  int i = blockIdx.x * blockDim.x + threadIdx.x;  // i = t*32 + e
  if (i < 32768) {
    if (W[i] != 0.f) {
      int t = i >> 5, e = i & 31;
      int p = atomicAdd(&counts[e], 1);
      tok[e * 1024 + p] = t;
    }
  }
}

// ---------------- planner: work items + compacted row bases ----------------
// plan[0] = n_items; plan[1..192] = (e<<16)|m0 (m0 local, 64-row tiles);
// plan[224+e] = base row of expert e in the compacted X/act buffers.
__global__ void plan_kernel(const int* __restrict__ counts, int* __restrict__ plan) {
  if (threadIdx.x != 0 || blockIdx.x != 0) return;
  int n = 0, base = 0;
  for (int e = 0; e < 32; e++) {
    int c = counts[e];
    plan[224 + e] = base;
    for (int m0 = 0; m0 < c; m0 += 64) plan[1 + n++] = (e << 16) | m0;
    base += (c + 63) & ~63;
  }
  plan[0] = n;
}

// ---------------- gather selected token rows into compacted Xc ----------------
// 2 rows per block (128 threads/row, short8 each). Zero-fills pad rows.
__global__ void gather_rows_kernel(const unsigned short* __restrict__ xb,
                                   const int* __restrict__ counts,
                                   const int* __restrict__ tok,
                                   const int* __restrict__ plan,
                                   unsigned short* __restrict__ Xc) {
  int row = blockIdx.x * 2 + (threadIdx.x >> 7);  // (e,r) flat, 0..32767
  int e = row >> 10, r = row & 1023;
  int cnt = counts[e];
  int pad = (cnt + 63) & ~63;
  if (r >= pad) return;
  long drow = plan[224 + e] + r;
  int c8 = (threadIdx.x & 127) * 8;
  if (r < cnt) {
    long tk = tok[e * 1024 + r];
    *(short8v*)(Xc + drow * 1024 + c8) = *(const short8v*)(xb + tk * 1024 + c8);
  } else {
    short8v z = {0, 0, 0, 0, 0, 0, 0, 0};
    *(short8v*)(Xc + drow * 1024 + c8) = z;
  }
}

// ---------------- fused g/u GEMM (64x128 tile) + silu*u*W epilogue ----------------
// Expert mode (plan!=null): blockIdx.y = work item; A rows at plan-base offsets.
// Dense mode (plan==null): e=0, m0=blockIdx.y*64, all rows valid, weight 1.
__global__ __launch_bounds__(256) void gu64_kernel(
    const unsigned short* __restrict__ A, const unsigned short* __restrict__ BgAll,
    const unsigned short* __restrict__ BuAll, unsigned short* __restrict__ Act,
    const int* __restrict__ plan, const int* __restrict__ counts,
    const int* __restrict__ tok, const float* __restrict__ W,
    int K, int ldO, long strideB) {
  __shared__ unsigned short As[64 * 64];
  __shared__ unsigned short Bgs[128 * 64];
  __shared__ unsigned short Bus[128 * 64];
  int e, m0, count;
  long abase;
  if (plan) {
    if ((int)blockIdx.y >= plan[0]) return;
    int it = plan[1 + blockIdx.y];
    e = it >> 16; m0 = it & 0xffff;
    count = counts[e];
    abase = plan[224 + e];
  } else {
    e = 0; m0 = blockIdx.y * 64; count = 1 << 30; abase = 0;
  }
  int n0 = blockIdx.x * 128;
  const unsigned short* Ae = A + abase * K;
  const unsigned short* Bg = BgAll + (long)e * strideB;
  const unsigned short* Bu = BuAll + (long)e * strideB;
  unsigned short* ActE = Act + abase * ldO;

  int tid = threadIdx.x, lane = tid & 63, w = tid >> 6;
  int lrow = lane >> 3, lslot = lane & 7, csrc = lslot ^ lrow;
  int wr = w >> 1, wc = w & 1, lm = lane & 15, lk = lane >> 4;

  f32x4 zero = {0.f, 0.f, 0.f, 0.f};
  f32x4 accg[2][4], accu[2][4];
#pragma unroll
  for (int mi = 0; mi < 2; mi++)
#pragma unroll
    for (int ni = 0; ni < 4; ni++) { accg[mi][ni] = zero; accu[mi][ni] = zero; }

  for (int k0 = 0; k0 < K; k0 += 64) {
    __syncthreads();
#pragma unroll
    for (int r = 0; r < 2; r++) {
      int s = w * 2 + r;
      GLOAD_LDS(Ae + (long)(m0 + s * 8 + lrow) * K + k0 + csrc * 8, As + s * 512);
    }
#pragma unroll
    for (int r = 0; r < 4; r++) {
      int s = w * 4 + r;
      GLOAD_LDS(Bg + (long)(n0 + s * 8 + lrow) * K + k0 + csrc * 8, Bgs + s * 512);
    }
#pragma unroll
    for (int r = 0; r < 4; r++) {
      int s = w * 4 + r;
      GLOAD_LDS(Bu + (long)(n0 + s * 8 + lrow) * K + k0 + csrc * 8, Bus + s * 512);
    }
    __syncthreads();
#pragma unroll
    for (int ks = 0; ks < 2; ks++) {
      short8v af[2], bg[4], bu[4];
#pragma unroll
      for (int mi = 0; mi < 2; mi++) {
        int rA = wr * 32 + mi * 16 + lm;
        int cA = ks * 4 + lk;
        af[mi] = *(const short8v*)(As + rA * 64 + ((cA ^ (rA & 7)) * 8));
      }
#pragma unroll
      for (int ni = 0; ni < 4; ni++) {
        int rB = wc * 64 + ni * 16 + lm;
        int cB = ks * 4 + lk;
        bg[ni] = *(const short8v*)(Bgs + rB * 64 + ((cB ^ (rB & 7)) * 8));
        bu[ni] = *(const short8v*)(Bus + rB * 64 + ((cB ^ (rB & 7)) * 8));
      }
#pragma unroll
      for (int mi = 0; mi < 2; mi++)
#pragma unroll
        for (int ni = 0; ni < 4; ni++) {
          accg[mi][ni] = __builtin_amdgcn_mfma_f32_16x16x32_bf16(af[mi], bg[ni],
                                                                 accg[mi][ni], 0, 0, 0);
          accu[mi][ni] = __builtin_amdgcn_mfma_f32_16x16x32_bf16(af[mi], bu[ni],
                                                                 accu[mi][ni], 0, 0, 0);
        }
    }
  }
#pragma unroll
  for (int mi = 0; mi < 2; mi++) {
#pragma unroll
    for (int j = 0; j < 4; j++) {
      int row = m0 + wr * 32 + mi * 16 + lk * 4 + j;
      if (row >= count) continue;
      float wv = 1.f;
      if (W) wv = W[tok[(long)e * 1024 + row] * 32 + e];
#pragma unroll
      for (int ni = 0; ni < 4; ni++) {
        int col = n0 + wc * 64 + ni * 16 + lm;
        float gf = accg[mi][ni][j], uf = accu[mi][ni][j];
        ActE[(long)row * ldO + col] = f2bf(gf / (1.f + expf(-gf)) * uf * wv);
      }
    }
  }
}

// ---------------- down projection (64x128 tile), fp32 atomic scatter-add ----------------
__global__ __launch_bounds__(256) void down64_kernel(
    const unsigned short* __restrict__ A, const unsigned short* __restrict__ BAll,
    float* __restrict__ C, const int* __restrict__ plan, const int* __restrict__ counts,
    const int* __restrict__ tok, int K, long strideB) {
  __shared__ unsigned short As[64 * 64];
  __shared__ unsigned short Bs[128 * 64];
  int e, m0, count;
  long abase;
  if (plan) {
    if ((int)blockIdx.y >= plan[0]) return;
    int it = plan[1 + blockIdx.y];
    e = it >> 16; m0 = it & 0xffff;
    count = counts[e];
    abase = plan[224 + e];
  } else {
    e = 0; m0 = blockIdx.y * 64; count = 1 << 30; abase = 0;
  }
  int n0 = blockIdx.x * 128;
  const unsigned short* Ae = A + abase * K;
  const unsigned short* Be = BAll + (long)e * strideB;

  int tid = threadIdx.x, lane = tid & 63, w = tid >> 6;
  int lrow = lane >> 3, lslot = lane & 7, csrc = lslot ^ lrow;
  int wr = w >> 1, wc = w & 1, lm = lane & 15, lk = lane >> 4;

  f32x4 zero = {0.f, 0.f, 0.f, 0.f};
  f32x4 acc[2][4];
#pragma unroll
  for (int mi = 0; mi < 2; mi++)
#pragma unroll
    for (int ni = 0; ni < 4; ni++) acc[mi][ni] = zero;

  for (int k0 = 0; k0 < K; k0 += 64) {
    __syncthreads();
#pragma unroll
    for (int r = 0; r < 2; r++) {
      int s = w * 2 + r;
      GLOAD_LDS(Ae + (long)(m0 + s * 8 + lrow) * K + k0 + csrc * 8, As + s * 512);
    }
#pragma unroll
    for (int r = 0; r < 4; r++) {
      int s = w * 4 + r;
      GLOAD_LDS(Be + (long)(n0 + s * 8 + lrow) * K + k0 + csrc * 8, Bs + s * 512);
    }
    __syncthreads();
#pragma unroll
    for (int ks = 0; ks < 2; ks++) {
      short8v af[2], bv[4];
#pragma unroll
      for (int mi = 0; mi < 2; mi++) {
        int rA = wr * 32 + mi * 16 + lm;
        int cA = ks * 4 + lk;
        af[mi] = *(const short8v*)(As + rA * 64 + ((cA ^ (rA & 7)) * 8));
      }
#pragma unroll
      for (int ni = 0; ni < 4; ni++) {
        int rB = wc * 64 + ni * 16 + lm;
        int cB = ks * 4 + lk;
        bv[ni] = *(const short8v*)(Bs + rB * 64 + ((cB ^ (rB & 7)) * 8));
      }
#pragma unroll
      for (int mi = 0; mi < 2; mi++)
#pragma unroll
        for (int ni = 0; ni < 4; ni++)
          acc[mi][ni] = __builtin_amdgcn_mfma_f32_16x16x32_bf16(af[mi], bv[ni],
                                                                acc[mi][ni], 0, 0, 0);
    }
  }
#pragma unroll
  for (int mi = 0; mi < 2; mi++) {
#pragma unroll
    for (int j = 0; j < 4; j++) {
      int row = m0 + wr * 32 + mi * 16 + lk * 4 + j;
      if (row >= count) continue;
      long tk = tok ? tok[(long)e * 1024 + row] : row;
#pragma unroll
      for (int ni = 0; ni < 4; ni++) {
        int col = n0 + wc * 64 + ni * 16 + lm;
        atomicAdd(&C[tk * 1024 + col], acc[mi][ni][j]);
      }
    }
  }
}

extern "C" void kernel_launch(void* const* d_in, const int* in_sizes, int n_in,
                              void* d_out, int out_size, void* d_ws, size_t ws_size,
                              hipStream_t stream) {
  const float* x  = (const float*)d_in[0];
  const float* gw = (const float*)d_in[1];
  const float* gb = (const float*)d_in[2];
  const float* eg = (const float*)d_in[3];
  const float* eu = (const float*)d_in[4];
  const float* ed = (const float*)d_in[5];
  const float* sg = (const float*)d_in[6];
  const float* su = (const float*)d_in[7];
  const float* sd = (const float*)d_in[8];
  float* out = (float*)d_out;

  char* ws = (char*)d_ws;
  size_t off = 0;
  auto alloc = [&](size_t bytes) {
    off = (off + 255) & ~(size_t)255;
    void* p = ws + off;
    off += bytes;
    return p;
  };
  unsigned short* xb    = (unsigned short*)alloc(1048576L * 2);
  unsigned short* egb   = (unsigned short*)alloc(16777216L * 2);
  unsigned short* eub   = (unsigned short*)alloc(16777216L * 2);
  unsigned short* edb   = (unsigned short*)alloc(16777216L * 2);
  unsigned short* sgb   = (unsigned short*)alloc(1048576L * 2);
  unsigned short* sub   = (unsigned short*)alloc(1048576L * 2);
  unsigned short* sdb   = (unsigned short*)alloc(1048576L * 2);
  float*          Wrt   = (float*)alloc(1024L * 32 * 4);
  unsigned short* Xc    = (unsigned short*)alloc(10240L * 1024 * 2);  // compacted x rows
  unsigned short* act_c = (unsigned short*)alloc(10240L * 512 * 2);   // compacted act
  unsigned short* act_s = (unsigned short*)alloc(1048576L * 2);       // shared act
  int*            counts = (int*)alloc(32 * 4);
  int*            tok    = (int*)alloc(32L * 1024 * 4);
  int*            plan   = (int*)alloc(256 * 4);

  hipMemsetAsync(counts, 0, 32 * 4, stream);
  hipMemsetAsync(d_out, 0, (size_t)out_size * 4, stream);

  convert_kernel<<<1024, 256, 0, stream>>>(x, xb, 1048576L);
  convert_kernel<<<4096, 256, 0, stream>>>(eg, egb, 16777216L);
  convert_kernel<<<4096, 256, 0, stream>>>(eu, eub, 16777216L);
  convert_kernel<<<4096, 256, 0, stream>>>(ed, edb, 16777216L);
  convert_kernel<<<1024, 256, 0, stream>>>(sg, sgb, 1048576L);
  convert_kernel<<<1024, 256, 0, stream>>>(su, sub, 1048576L);
  convert_kernel<<<1024, 256, 0, stream>>>(sd, sdb, 1048576L);

  gate_kernel<<<1024, 256, 0, stream>>>(x, gw, gb, Wrt);
  build_lists_kernel<<<128, 256, 0, stream>>>(Wrt, counts, tok);
  plan_kernel<<<1, 64, 0, stream>>>(counts, plan);
  gather_rows_kernel<<<16384, 256, 0, stream>>>(xb, counts, tok, plan, Xc);

  dim3 blk(256);
  // expert path: fused g/u + act epilogue on compacted rows (work-list driven)
  gu64_kernel<<<dim3(4, 192), blk, 0, stream>>>(Xc, egb, eub, act_c, plan, counts, tok,
                                                Wrt, 1024, 512, 524288L);
  // shared path: dense rows, weight 1
  gu64_kernel<<<dim3(8, 16), blk, 0, stream>>>(xb, sgb, sub, act_s, nullptr, nullptr,
                                               nullptr, nullptr, 1024, 1024, 0L);
  // expert down: compacted rows, scatter-add
  down64_kernel<<<dim3(8, 192), blk, 0, stream>>>(act_c, edb, out, plan, counts, tok,
                                                  512, 524288L);
  // shared down: dense accumulate
  down64_kernel<<<dim3(8, 16), blk, 0, stream>>>(act_s, sdb, out, nullptr, nullptr,
                                                 nullptr, 1024, 0L);
}

// Round 10
// 411.737 us; speedup vs baseline: 1.3272x; 1.0592x over previous
//
#include <hip/hip_runtime.h>
#include <hip/hip_bf16.h>

// DeepseekV3 MoE calibrate: T=1024, H=1024, I=512, E=32, top-8.
// Round 10: (a) gate top-k rewritten register-only (round-9 PMC: gate 71us,
// VALUBusy 0.1% -> scratch-latency from runtime-indexed local arrays, rule #20);
// (b) merged gu/down work-list launches (expert + shared-as-e32);
// (c) converts fused 7 -> 2 launches. Round-9: 436us (gate 71, gu64 51).

typedef __attribute__((ext_vector_type(8))) short short8v;
typedef __attribute__((ext_vector_type(4))) float f32x4;

#define GLOAD_LDS(gp, lp)                                                      \
  __builtin_amdgcn_global_load_lds(                                            \
      (const __attribute__((address_space(1))) void*)(gp),                     \
      (__attribute__((address_space(3))) void*)(lp), 16, 0, 0)

__device__ __forceinline__ unsigned short f2bf(float f) {
  unsigned int u = __float_as_uint(f);
  u = (u + 0x7fffu + ((u >> 16) & 1u)) >> 16;
  return (unsigned short)u;
}

// ---------------- fused fp32 -> bf16 conversions ----------------
// 3 segments of 2^24 elements (eg, eu, ed).
__global__ void convert3_kernel(const float* __restrict__ s0, const float* __restrict__ s1,
                                const float* __restrict__ s2, unsigned short* __restrict__ d0,
                                unsigned short* __restrict__ d1, unsigned short* __restrict__ d2) {
  long i = ((long)blockIdx.x * blockDim.x + threadIdx.x) * 4;
  long stride = (long)gridDim.x * blockDim.x * 4;
  for (; i < 50331648L; i += stride) {
    int seg = (int)(i >> 24);
    long off = i & 16777215L;
    const float* s = seg == 0 ? s0 : (seg == 1 ? s1 : s2);
    unsigned short* d = seg == 0 ? d0 : (seg == 1 ? d1 : d2);
    float4 v = *(const float4*)(s + off);
    ushort4 o;
    o.x = f2bf(v.x); o.y = f2bf(v.y); o.z = f2bf(v.z); o.w = f2bf(v.w);
    *(ushort4*)(d + off) = o;
  }
}

// 4 segments of 2^20 elements (x, sg, su, sd).
__global__ void convert4_kernel(const float* __restrict__ s0, const float* __restrict__ s1,
                                const float* __restrict__ s2, const float* __restrict__ s3,
                                unsigned short* __restrict__ d0, unsigned short* __restrict__ d1,
                                unsigned short* __restrict__ d2, unsigned short* __restrict__ d3) {
  long i = ((long)blockIdx.x * blockDim.x + threadIdx.x) * 4;
  long stride = (long)gridDim.x * blockDim.x * 4;
  for (; i < 4194304L; i += stride) {
    int seg = (int)(i >> 20);
    long off = i & 1048575L;
    const float* s = seg == 0 ? s0 : (seg == 1 ? s1 : (seg == 2 ? s2 : s3));
    unsigned short* d = seg == 0 ? d0 : (seg == 1 ? d1 : (seg == 2 ? d2 : d3));
    float4 v = *(const float4*)(s + off);
    ushort4 o;
    o.x = f2bf(v.x); o.y = f2bf(v.y); o.z = f2bf(v.z); o.w = f2bf(v.w);
    *(ushort4*)(d + off) = o;
  }
}

// ---------------- routing (register-only top-k; no runtime-indexed arrays) ----------------
__global__ void gate_kernel(const float* __restrict__ x, const float* __restrict__ gw,
                            const float* __restrict__ gb, float* __restrict__ W) {
  int t = blockIdx.x;
  int tid = threadIdx.x;
  __shared__ float partial[256];
  __shared__ float logits[32];
  const float* xr = x + (long)t * 1024;
  int e = tid & 31, c = tid >> 5;
  const float* wr = gw + (long)e * 1024 + c * 128;
  const float* xc = xr + c * 128;
  float s = 0.f;
  for (int h = 0; h < 128; h += 4) {
    float4 xv = *(const float4*)(xc + h);
    float4 wv = *(const float4*)(wr + h);
    s += xv.x * wv.x + xv.y * wv.y + xv.z * wv.z + xv.w * wv.w;
  }
  partial[tid] = s;
  __syncthreads();
  if (tid < 32) {
    float l = 0.f;
    for (int cc = 0; cc < 8; cc++) l += partial[tid + 32 * cc];
    logits[tid] = l;
  }
  __syncthreads();
  if (tid == 0) {
    float scores[32], sc[32];
#pragma unroll
    for (int i = 0; i < 32; i++) {
      float s1 = 1.f / (1.f + expf(-logits[i]));
      scores[i] = s1;
      sc[i] = s1 + gb[i];
    }
    float gsc[4];
#pragma unroll
    for (int g = 0; g < 4; g++) {
      float m1 = -1e30f, m2 = -1e30f;
#pragma unroll
      for (int j = 0; j < 8; j++) {
        float v = sc[g * 8 + j];
        bool gt1 = v > m1;
        float nm2 = gt1 ? m1 : (v > m2 ? v : m2);
        m1 = gt1 ? v : m1;
        m2 = nm2;
      }
      gsc[g] = m1 + m2;
    }
    float b1 = gsc[0];
    int g1 = 0;
#pragma unroll
    for (int g = 1; g < 4; g++)
      if (gsc[g] > b1) { b1 = gsc[g]; g1 = g; }
    float b2 = -1e30f;
    int g2 = -1;
#pragma unroll
    for (int g = 0; g < 4; g++)
      if (g != g1 && gsc[g] > b2) { b2 = gsc[g]; g2 = g; }

    unsigned removed = 0;
    float tw[8]; int bi[8]; float wsum = 0.f;
#pragma unroll
    for (int k = 0; k < 8; k++) {
      float bv = -1e30f, bs = 0.f;
      int best = 0;
#pragma unroll
      for (int i = 0; i < 32; i++) {
        int g = i >> 3;
        float v = ((removed >> i) & 1u) ? -2e30f : ((g == g1 || g == g2) ? sc[i] : 0.0f);
        if (v > bv) { bv = v; best = i; bs = scores[i]; }
      }
      removed |= 1u << best;
      tw[k] = bs;
      bi[k] = best;
      wsum += bs;
    }
    float inv = 2.5f / (wsum + 1e-20f);
#pragma unroll
    for (int i = 0; i < 32; i++) {
      float v = 0.f;
#pragma unroll
      for (int k = 0; k < 8; k++) v = (bi[k] == i) ? tw[k] * inv : v;
      W[t * 32 + i] = v;
    }
  }
}

// ---------------- per-expert token lists ----------------
__global__ void build_lists_kernel(const float* __restrict__ W, int* __restrict__ counts,
                                   int* __restrict__ tok) {
  int i = blockIdx.x * blockDim.x + threadIdx.x;  // i = t*32 + e
  if (i < 32768) {
    if (W[i] != 0.f) {
      int t = i >> 5, e = i & 31;
      int p = atomicAdd(&counts[e], 1);
      tok[e * 1024 + p] = t;
    }
  }
}

// ---------------- planner ----------------
// plan[0]=n_gu, plan[1]=n_down; gu items at [8..], down items at [1024..];
// item = (e<<8)|(mt<<4)|n0t (e=32 -> shared). bases at plan[4096+e].
__global__ void plan_kernel(const int* __restrict__ counts, int* __restrict__ plan) {
  if (threadIdx.x != 0 || blockIdx.x != 0) return;
  int n_gu = 0, n_down = 0, base = 0;
  // shared first (longest items -> LPT scheduling)
  for (int mt = 0; mt < 16; mt++)
    for (int n0t = 0; n0t < 8; n0t++) {
      plan[8 + n_gu++] = (32 << 8) | (mt << 4) | n0t;
      plan[1024 + n_down++] = (32 << 8) | (mt << 4) | n0t;
    }
  for (int e = 0; e < 32; e++) {
    int c = counts[e];
    plan[4096 + e] = base;
    int mts = (c + 63) >> 6;
    for (int mt = 0; mt < mts; mt++) {
      for (int n0t = 0; n0t < 4; n0t++) plan[8 + n_gu++] = (e << 8) | (mt << 4) | n0t;
      for (int n0t = 0; n0t < 8; n0t++) plan[1024 + n_down++] = (e << 8) | (mt << 4) | n0t;
    }
    base += mts * 64;
  }
  plan[0] = n_gu;
  plan[1] = n_down;
}

// ---------------- gather selected token rows into compacted Xc ----------------
__global__ void gather_rows_kernel(const unsigned short* __restrict__ xb,
                                   const int* __restrict__ counts,
                                   const int* __restrict__ tok,
                                   const int* __restrict__ plan,
                                   unsigned short* __restrict__ Xc) {
  int row = blockIdx.x * 2 + (threadIdx.x >> 7);  // (e,r) flat
  int e = row >> 10, r = row & 1023;
  int cnt = counts[e];
  int pad = (cnt + 63) & ~63;
  if (r >= pad) return;
  long drow = plan[4096 + e] + r;
  int c8 = (threadIdx.x & 127) * 8;
  if (r < cnt) {
    long tk = tok[e * 1024 + r];
    *(short8v*)(Xc + drow * 1024 + c8) = *(const short8v*)(xb + tk * 1024 + c8);
  } else {
    short8v z = {0, 0, 0, 0, 0, 0, 0, 0};
    *(short8v*)(Xc + drow * 1024 + c8) = z;
  }
}

// ---------------- fused g/u GEMM (64x128 tile) + silu*u*W epilogue, all in one grid ----
__global__ __launch_bounds__(256) void gu_all_kernel(
    const unsigned short* __restrict__ Xc, const unsigned short* __restrict__ xb,
    const unsigned short* __restrict__ egb, const unsigned short* __restrict__ eub,
    const unsigned short* __restrict__ sgb, const unsigned short* __restrict__ sub,
    unsigned short* __restrict__ act_c, unsigned short* __restrict__ act_s,
    const int* __restrict__ plan, const int* __restrict__ counts,
    const int* __restrict__ tok, const float* __restrict__ W) {
  __shared__ unsigned short As[64 * 64];
  __shared__ unsigned short Bgs[128 * 64];
  __shared__ unsigned short Bus[128 * 64];
  int id = blockIdx.x;
  if (id >= plan[0]) return;
  int it = plan[8 + id];
  int e = it >> 8, mt = (it >> 4) & 15, n0 = (it & 15) * 128;
  int m0 = mt * 64;
  bool expert = e < 32;
  const unsigned short *Ae, *Bg, *Bu;
  unsigned short* Act;
  int count, ldO;
  if (expert) {
    int abase = plan[4096 + e];
    Ae = Xc + (long)abase * 1024;
    Bg = egb + (long)e * 524288;
    Bu = eub + (long)e * 524288;
    Act = act_c + (long)abase * 512;
    ldO = 512;
    count = counts[e];
  } else {
    Ae = xb; Bg = sgb; Bu = sub; Act = act_s; ldO = 1024; count = 1024;
  }

  int tid = threadIdx.x, lane = tid & 63, w = tid >> 6;
  int lrow = lane >> 3, lslot = lane & 7, csrc = lslot ^ lrow;
  int wr = w >> 1, wc = w & 1, lm = lane & 15, lk = lane >> 4;

  f32x4 zero = {0.f, 0.f, 0.f, 0.f};
  f32x4 accg[2][4], accu[2][4];
#pragma unroll
  for (int mi = 0; mi < 2; mi++)
#pragma unroll
    for (int ni = 0; ni < 4; ni++) { accg[mi][ni] = zero; accu[mi][ni] = zero; }

  for (int k0 = 0; k0 < 1024; k0 += 64) {
    __syncthreads();
#pragma unroll
    for (int r = 0; r < 2; r++) {
      int s = w * 2 + r;
      GLOAD_LDS(Ae + (long)(m0 + s * 8 + lrow) * 1024 + k0 + csrc * 8, As + s * 512);
    }
#pragma unroll
    for (int r = 0; r < 4; r++) {
      int s = w * 4 + r;
      GLOAD_LDS(Bg + (long)(n0 + s * 8 + lrow) * 1024 + k0 + csrc * 8, Bgs + s * 512);
    }
#pragma unroll
    for (int r = 0; r < 4; r++) {
      int s = w * 4 + r;
      GLOAD_LDS(Bu + (long)(n0 + s * 8 + lrow) * 1024 + k0 + csrc * 8, Bus + s * 512);
    }
    __syncthreads();
#pragma unroll
    for (int ks = 0; ks < 2; ks++) {
      short8v af[2], bg[4], bu[4];
#pragma unroll
      for (int mi = 0; mi < 2; mi++) {
        int rA = wr * 32 + mi * 16 + lm;
        int cA = ks * 4 + lk;
        af[mi] = *(const short8v*)(As + rA * 64 + ((cA ^ (rA & 7)) * 8));
      }
#pragma unroll
      for (int ni = 0; ni < 4; ni++) {
        int rB = wc * 64 + ni * 16 + lm;
        int cB = ks * 4 + lk;
        bg[ni] = *(const short8v*)(Bgs + rB * 64 + ((cB ^ (rB & 7)) * 8));
        bu[ni] = *(const short8v*)(Bus + rB * 64 + ((cB ^ (rB & 7)) * 8));
      }
#pragma unroll
      for (int mi = 0; mi < 2; mi++)
#pragma unroll
        for (int ni = 0; ni < 4; ni++) {
          accg[mi][ni] = __builtin_amdgcn_mfma_f32_16x16x32_bf16(af[mi], bg[ni],
                                                                 accg[mi][ni], 0, 0, 0);
          accu[mi][ni] = __builtin_amdgcn_mfma_f32_16x16x32_bf16(af[mi], bu[ni],
                                                                 accu[mi][ni], 0, 0, 0);
        }
    }
  }
#pragma unroll
  for (int mi = 0; mi < 2; mi++) {
#pragma unroll
    for (int j = 0; j < 4; j++) {
      int row = m0 + wr * 32 + mi * 16 + lk * 4 + j;
      if (row >= count) continue;
      float wv = expert ? W[tok[(long)e * 1024 + row] * 32 + e] : 1.f;
#pragma unroll
      for (int ni = 0; ni < 4; ni++) {
        int col = n0 + wc * 64 + ni * 16 + lm;
        float gf = accg[mi][ni][j], uf = accu[mi][ni][j];
        Act[(long)row * ldO + col] = f2bf(gf / (1.f + expf(-gf)) * uf * wv);
      }
    }
  }
}

// ---------------- down projection (64x128), fp32 atomic scatter-add, all in one grid ----
__global__ __launch_bounds__(256) void down_all_kernel(
    const unsigned short* __restrict__ act_c, const unsigned short* __restrict__ act_s,
    const unsigned short* __restrict__ edb, const unsigned short* __restrict__ sdb,
    float* __restrict__ C, const int* __restrict__ plan, const int* __restrict__ counts,
    const int* __restrict__ tok) {
  __shared__ unsigned short As[64 * 64];
  __shared__ unsigned short Bs[128 * 64];
  int id = blockIdx.x;
  if (id >= plan[1]) return;
  int it = plan[1024 + id];
  int e = it >> 8, mt = (it >> 4) & 15, n0 = (it & 15) * 128;
  int m0 = mt * 64;
  bool expert = e < 32;
  const unsigned short *Ae, *Be;
  int count, K;
  if (expert) {
    int abase = plan[4096 + e];
    Ae = act_c + (long)abase * 512;
    Be = edb + (long)e * 524288;
    K = 512;
    count = counts[e];
  } else {
    Ae = act_s; Be = sdb; K = 1024; count = 1024;
  }

  int tid = threadIdx.x, lane = tid & 63, w = tid >> 6;
  int lrow = lane >> 3, lslot = lane & 7, csrc = lslot ^ lrow;
  int wr = w >> 1, wc = w & 1, lm = lane & 15, lk = lane >> 4;

  f32x4 zero = {0.f, 0.f, 0.f, 0.f};
  f32x4 acc[2][4];
#pragma unroll
  for (int mi = 0; mi < 2; mi++)
#pragma unroll
    for (int ni = 0; ni < 4; ni++) acc[mi][ni] = zero;

  for (int k0 = 0; k0 < K; k0 += 64) {
    __syncthreads();
#pragma unroll
    for (int r = 0; r < 2; r++) {
      int s = w * 2 + r;
      GLOAD_LDS(Ae + (long)(m0 + s * 8 + lrow) * K + k0 + csrc * 8, As + s * 512);
    }
#pragma unroll
    for (int r = 0; r < 4; r++) {
      int s = w * 4 + r;
      GLOAD_LDS(Be + (long)(n0 + s * 8 + lrow) * K + k0 + csrc * 8, Bs + s * 512);
    }
    __syncthreads();
#pragma unroll
    for (int ks = 0; ks < 2; ks++) {
      short8v af[2], bv[4];
#pragma unroll
      for (int mi = 0; mi < 2; mi++) {
        int rA = wr * 32 + mi * 16 + lm;
        int cA = ks * 4 + lk;
        af[mi] = *(const short8v*)(As + rA * 64 + ((cA ^ (rA & 7)) * 8));
      }
#pragma unroll
      for (int ni = 0; ni < 4; ni++) {
        int rB = wc * 64 + ni * 16 + lm;
        int cB = ks * 4 + lk;
        bv[ni] = *(const short8v*)(Bs + rB * 64 + ((cB ^ (rB & 7)) * 8));
      }
#pragma unroll
      for (int mi = 0; mi < 2; mi++)
#pragma unroll
        for (int ni = 0; ni < 4; ni++)
          acc[mi][ni] = __builtin_amdgcn_mfma_f32_16x16x32_bf16(af[mi], bv[ni],
                                                                acc[mi][ni], 0, 0, 0);
    }
  }
#pragma unroll
  for (int mi = 0; mi < 2; mi++) {
#pragma unroll
    for (int j = 0; j < 4; j++) {
      int row = m0 + wr * 32 + mi * 16 + lk * 4 + j;
      if (row >= count) continue;
      long tk = expert ? tok[(long)e * 1024 + row] : row;
#pragma unroll
      for (int ni = 0; ni < 4; ni++) {
        int col = n0 + wc * 64 + ni * 16 + lm;
        atomicAdd(&C[tk * 1024 + col], acc[mi][ni][j]);
      }
    }
  }
}

extern "C" void kernel_launch(void* const* d_in, const int* in_sizes, int n_in,
                              void* d_out, int out_size, void* d_ws, size_t ws_size,
                              hipStream_t stream) {
  const float* x  = (const float*)d_in[0];
  const float* gw = (const float*)d_in[1];
  const float* gb = (const float*)d_in[2];
  const float* eg = (const float*)d_in[3];
  const float* eu = (const float*)d_in[4];
  const float* ed = (const float*)d_in[5];
  const float* sg = (const float*)d_in[6];
  const float* su = (const float*)d_in[7];
  const float* sd = (const float*)d_in[8];
  float* out = (float*)d_out;

  char* ws = (char*)d_ws;
  size_t off = 0;
  auto alloc = [&](size_t bytes) {
    off = (off + 255) & ~(size_t)255;
    void* p = ws + off;
    off += bytes;
    return p;
  };
  unsigned short* xb    = (unsigned short*)alloc(1048576L * 2);
  unsigned short* egb   = (unsigned short*)alloc(16777216L * 2);
  unsigned short* eub   = (unsigned short*)alloc(16777216L * 2);
  unsigned short* edb   = (unsigned short*)alloc(16777216L * 2);
  unsigned short* sgb   = (unsigned short*)alloc(1048576L * 2);
  unsigned short* sub   = (unsigned short*)alloc(1048576L * 2);
  unsigned short* sdb   = (unsigned short*)alloc(1048576L * 2);
  float*          Wrt   = (float*)alloc(1024L * 32 * 4);
  unsigned short* Xc    = (unsigned short*)alloc(10240L * 1024 * 2);
  unsigned short* act_c = (unsigned short*)alloc(10240L * 512 * 2);
  unsigned short* act_s = (unsigned short*)alloc(1048576L * 2);
  int*            counts = (int*)alloc(32 * 4);
  int*            tok    = (int*)alloc(32L * 1024 * 4);
  int*            plan   = (int*)alloc(8192 * 4);

  hipMemsetAsync(counts, 0, 32 * 4, stream);
  hipMemsetAsync(d_out, 0, (size_t)out_size * 4, stream);

  convert3_kernel<<<4096, 256, 0, stream>>>(eg, eu, ed, egb, eub, edb);
  convert4_kernel<<<1024, 256, 0, stream>>>(x, sg, su, sd, xb, sgb, sub, sdb);

  gate_kernel<<<1024, 256, 0, stream>>>(x, gw, gb, Wrt);
  build_lists_kernel<<<128, 256, 0, stream>>>(Wrt, counts, tok);
  plan_kernel<<<1, 64, 0, stream>>>(counts, plan);
  gather_rows_kernel<<<16384, 256, 0, stream>>>(xb, counts, tok, plan, Xc);

  gu_all_kernel<<<768, 256, 0, stream>>>(Xc, xb, egb, eub, sgb, sub, act_c, act_s,
                                         plan, counts, tok, Wrt);
  down_all_kernel<<<1408, 256, 0, stream>>>(act_c, act_s, edb, sdb, out, plan, counts,
                                            tok);
}